// Round 14
// baseline (273.307 us; speedup 1.0000x reference)
//
#include <hip/hip_runtime.h>
#include <hip/hip_bf16.h>
#include <hip/hip_fp16.h>

// ---------------------------------------------------------------------------
// GAT 2-layer pipeline. R14: agg kernels reverted to measured-optimal R12
// shapes (VGPR32, 8 waves/SIMD). Sort chain simplified: per-bucket totals +
// tiny 391-scan + run-reservation scatter (no flatN scans). wpack fused into
// hist dispatch. Fused attention scores in GEMM epilogue; single-pass softmax
// w/o max-sub; MFMA bf16 GEMMs.
// ---------------------------------------------------------------------------

#define NNODES 50000
#define NODE_SHIFT 7                       // 128 nodes per bucket
#define BKTS ((NNODES + 127) / 128)        // 391
#define CHUNK 4096                         // edges per histogram/scatter block
#define CAP 8192                           // max edges per bucket (mean ~4224)

typedef __bf16 bf16x8 __attribute__((ext_vector_type(8)));
typedef float f32x4 __attribute__((ext_vector_type(4)));

// ---- hist (per-bucket totals) + W-repack fused -----------------------------
__global__ __launch_bounds__(256) void hist_wpack_k(
    const int* __restrict__ edst, int E, int Etot, int NB,
    int* __restrict__ btot,
    const float* __restrict__ W1, const float* __restrict__ W2,
    __hip_bfloat16* __restrict__ Wp1, __hip_bfloat16* __restrict__ Wp2) {
    if ((int)blockIdx.x >= NB) {
        constexpr int TOT1 = 8 * 4 * 64;   // COLS=128
        constexpr int TOT2 = 4 * 4 * 64;   // COLS=64
        int i = (blockIdx.x - NB) * 256 + threadIdx.x;
        if (i < TOT1) {
            int l = i & 63, s = (i >> 6) & 3, t = i >> 8;
            int quad = l >> 4, col = l & 15;
#pragma unroll
            for (int j = 0; j < 8; ++j) {
                float f = W1[(s * 32 + quad * 8 + j) * 128 + t * 16 + col];
                Wp1[(size_t)i * 8 + j] = __float2bfloat16(f);
            }
        } else if (i < TOT1 + TOT2) {
            int i2 = i - TOT1;
            int l = i2 & 63, s = (i2 >> 6) & 3, t = i2 >> 8;
            int quad = l >> 4, col = l & 15;
#pragma unroll
            for (int j = 0; j < 8; ++j) {
                float f = W2[(s * 32 + quad * 8 + j) * 64 + t * 16 + col];
                Wp2[(size_t)i2 * 8 + j] = __float2bfloat16(f);
            }
        }
        return;
    }
    __shared__ int h[BKTS];
    for (int b = threadIdx.x; b < BKTS; b += 256) h[b] = 0;
    __syncthreads();
    const int e0 = blockIdx.x * CHUNK;
    const int e1 = min(e0 + CHUNK, Etot);
    for (int i = e0 + threadIdx.x; i < e1; i += 256) {
        int d = (i < E) ? edst[i] : (i - E);
        atomicAdd(&h[d >> NODE_SHIFT], 1);
    }
    __syncthreads();
    for (int b = threadIdx.x; b < BKTS; b += 256)
        if (h[b] > 0) atomicAdd(&btot[b], h[b]);
}

// ---- tiny scan over BKTS bucket totals -> base[] (excl, +end) and cursor[] -
__global__ __launch_bounds__(256) void scan_small_k(
    const int* __restrict__ btot, int* __restrict__ base,
    int* __restrict__ cursor, int nb) {
    __shared__ int sA[256];
    const int t = threadIdx.x;
    int carry = 0;
    for (int b0 = 0; b0 < nb; b0 += 256) {
        int i = b0 + t;
        int v = (i < nb) ? btot[i] : 0;
        sA[t] = v;
        __syncthreads();
        for (int off = 1; off < 256; off <<= 1) {
            int u = (t >= off) ? sA[t - off] : 0;
            __syncthreads();
            sA[t] += u;
            __syncthreads();
        }
        if (i < nb) {
            int incl = sA[t] + carry;
            int excl = incl - v;
            base[i] = excl;
            cursor[i] = excl;
            if (i == nb - 1) base[nb] = incl;   // == Etot
        }
        carry += sA[255];
        __syncthreads();
    }
}

// ---- scatter with per-(block,bucket) run reservation -----------------------
__global__ __launch_bounds__(256) void scatter_bucket_k(
    const int* __restrict__ esrc, const int* __restrict__ edst,
    int E, int Etot, int* __restrict__ cursor,
    unsigned int* __restrict__ gbucket) {
    __shared__ int h[BKTS], rb[BKTS], lcur[BKTS];
    for (int b = threadIdx.x; b < BKTS; b += 256) { h[b] = 0; lcur[b] = 0; }
    __syncthreads();
    const int e0 = blockIdx.x * CHUNK;
    const int e1 = min(e0 + CHUNK, Etot);
    // pass 1: count this chunk's bucket histogram
    for (int i = e0 + threadIdx.x; i < e1; i += 256) {
        int d = (i < E) ? edst[i] : (i - E);
        atomicAdd(&h[d >> NODE_SHIFT], 1);
    }
    __syncthreads();
    // reserve contiguous runs
    for (int b = threadIdx.x; b < BKTS; b += 256)
        if (h[b] > 0) rb[b] = atomicAdd(&cursor[b], h[b]);
    __syncthreads();
    // pass 2: write runs (edges re-read; L2-hot)
    for (int i = e0 + threadIdx.x; i < e1; i += 256) {
        int s, d;
        if (i < E) { s = esrc[i]; d = edst[i]; }
        else       { s = i - E;   d = i - E; }
        int k = d >> NODE_SHIFT;
        int pos = rb[k] + atomicAdd(&lcur[k], 1);
        gbucket[pos] = ((unsigned)(d & 127) << 16) | (unsigned)s;
    }
}

// ---- finalize: per-bucket LDS counting sort -> ssrc (ushort) + rowptr ------
__global__ __launch_bounds__(256) void finalize_k(
    const unsigned int* __restrict__ gbucket, const int* __restrict__ base,
    unsigned short* __restrict__ ssrc, int* __restrict__ rowptr, int Nn) {
    const int b = blockIdx.x;
    const int bbase = base[b];
    const int end = base[b + 1];
    const int cnt = end - bbase;
    const int t = threadIdx.x;

    __shared__ unsigned int keys[CAP];
    __shared__ int hist[128], sA[128], cur[128];

    for (int i = t; i < cnt; i += 256) keys[i] = gbucket[bbase + i];
    if (t < 128) hist[t] = 0;
    __syncthreads();
    for (int i = t; i < cnt; i += 256) atomicAdd(&hist[keys[i] >> 16], 1);
    __syncthreads();
    if (t < 128) sA[t] = hist[t];
    __syncthreads();
    for (int off = 1; off < 128; off <<= 1) {
        int u = 0;
        if (t < 128 && t >= off) u = sA[t - off];
        __syncthreads();
        if (t < 128) sA[t] += u;
        __syncthreads();
    }
    if (t < 128) {
        int excl = sA[t] - hist[t];
        cur[t] = excl;
        int node = b * 128 + t;
        if (node <= Nn) rowptr[node] = bbase + excl;  // node==Nn -> rowptr[N]=Etot
    }
    __syncthreads();
    for (int i = t; i < cnt; i += 256) {
        unsigned k = keys[i];
        int p = atomicAdd(&cur[k >> 16], 1);
        ssrc[bbase + p] = (unsigned short)(k & 0xFFFFu);
    }
}

// ---------- MFMA GEMM: Y = X @ W, bf16 out, fused attention scores ---------
template <int COLS, bool IN_BF16>
__global__ __launch_bounds__(256) void gemm_mfma_k(
    const void* __restrict__ Xv, const __hip_bfloat16* __restrict__ Wp,
    __hip_bfloat16* __restrict__ Y,
    const float* __restrict__ atts, const float* __restrict__ attd,
    float* __restrict__ a_s, float* __restrict__ a_d, int M) {
    constexpr int NH = (COLS == 128) ? 4 : 1;
    const int wid = threadIdx.x >> 6, lane = threadIdx.x & 63;
    const int tile = blockIdx.x * 4 + wid;
    if (tile * 16 >= M) return;
    const int quad = lane >> 4, col = lane & 15;
    const int row = tile * 16 + col;

    bf16x8 afr[4];
    if (IN_BF16) {
        const __hip_bfloat16* X = (const __hip_bfloat16*)Xv;
#pragma unroll
        for (int s = 0; s < 4; ++s)
            afr[s] = *(const bf16x8*)(X + (size_t)row * 128 + s * 32 + quad * 8);
    } else {
        const float* X = (const float*)Xv;
#pragma unroll
        for (int s = 0; s < 4; ++s) {
            const float4* p = (const float4*)(X + (size_t)row * 128 + s * 32 + quad * 8);
            float4 f0 = p[0], f1 = p[1];
            afr[s][0] = (__bf16)f0.x; afr[s][1] = (__bf16)f0.y;
            afr[s][2] = (__bf16)f0.z; afr[s][3] = (__bf16)f0.w;
            afr[s][4] = (__bf16)f1.x; afr[s][5] = (__bf16)f1.y;
            afr[s][6] = (__bf16)f1.z; afr[s][7] = (__bf16)f1.w;
        }
    }

    float asp[4][NH], adp[4][NH];
#pragma unroll
    for (int r = 0; r < 4; ++r)
#pragma unroll
        for (int h = 0; h < NH; ++h) { asp[r][h] = 0.f; adp[r][h] = 0.f; }

    const bf16x8* Wp8 = (const bf16x8*)Wp;
#pragma unroll
    for (int t = 0; t < COLS / 16; ++t) {
        f32x4 acc = {0.f, 0.f, 0.f, 0.f};
#pragma unroll
        for (int s = 0; s < 4; ++s) {
            bf16x8 bfr = Wp8[(t * 4 + s) * 64 + lane];
            acc = __builtin_amdgcn_mfma_f32_16x16x32_bf16(afr[s], bfr, acc, 0, 0, 0);
        }
        const int gc = t * 16 + col;          // global column
        const int h = (NH == 4) ? (t >> 1) : 0;
        const float ws = atts[gc], wd = attd[gc];
#pragma unroll
        for (int r = 0; r < 4; ++r) {
            asp[r][h] += acc[r] * ws;
            adp[r][h] += acc[r] * wd;
            Y[(size_t)(tile * 16 + quad * 4 + r) * COLS + gc] = __float2bfloat16(acc[r]);
        }
    }

#pragma unroll
    for (int off = 1; off <= 8; off <<= 1) {
#pragma unroll
        for (int r = 0; r < 4; ++r)
#pragma unroll
            for (int h = 0; h < NH; ++h) {
                asp[r][h] += __shfl_xor(asp[r][h], off);
                adp[r][h] += __shfl_xor(adp[r][h], off);
            }
    }
    if (col == 0) {
#pragma unroll
        for (int r = 0; r < 4; ++r) {
            int rw = tile * 16 + quad * 4 + r;
#pragma unroll
            for (int h = 0; h < NH; ++h) {
                a_s[rw * NH + h] = asp[r][h];
                a_d[rw * NH + h] = adp[r][h];
            }
        }
    }
}

// ---- layer 1: batched gathers + single-pass softmax + bias/BN/ELU ---------
// R12 shape: quarter-waves (16 lanes x 8ch), 4 edges/qwave, VGPR-lean.
__global__ __launch_bounds__(256) void agg1_k(
    const int* __restrict__ rowptr, const unsigned short* __restrict__ ssrc,
    const __hip_bfloat16* __restrict__ xw,
    const float* __restrict__ a_s, const float* __restrict__ a_d,
    const float* __restrict__ bias,
    const float* __restrict__ gamma, const float* __restrict__ beta,
    const float* __restrict__ mean, const float* __restrict__ var,
    __hip_bfloat16* __restrict__ out, int Nn) {
    int n = (blockIdx.x * blockDim.x + threadIdx.x) >> 6;
    int lane = threadIdx.x & 63;
    if (n >= Nn) return;
    const int r0 = rowptr[n];
    const int deg = rowptr[n + 1] - r0;
    const int g = lane >> 4, q = lane & 15;
    const int c0 = q * 8;          // channels c0..c0+7
    const int h = q >> 2;          // head = c0/32
    const float adh = a_d[n * 4 + h];

    float ssum = 0.f;
    float acc[8];
#pragma unroll
    for (int k = 0; k < 8; ++k) acc[k] = 0.f;

    int j = 0;
    for (; j + 16 <= deg; j += 16) {
        int sid[4];
#pragma unroll
        for (int b = 0; b < 4; ++b) sid[b] = ssrc[r0 + j + b * 4 + g];
        float as[4];
        bf16x8 f[4];
#pragma unroll
        for (int b = 0; b < 4; ++b) {
            as[b] = a_s[sid[b] * 4 + h];
            f[b] = *(const bf16x8*)(xw + (size_t)sid[b] * 128 + c0);
        }
#pragma unroll
        for (int b = 0; b < 4; ++b) {
            float e = as[b] + adh;
            e = (e > 0.f) ? e : 0.2f * e;
            float p = __expf(e);
            ssum += p;
#pragma unroll
            for (int k = 0; k < 8; ++k) acc[k] += p * (float)f[b][k];
        }
    }
    for (; j < deg; j += 4) {
        int jj = j + g;
        bool ok = jj < deg;
        int sid = ssrc[r0 + (ok ? jj : j)];
        float e = a_s[sid * 4 + h] + adh;
        e = (e > 0.f) ? e : 0.2f * e;
        float p = ok ? __expf(e) : 0.f;
        ssum += p;
        bf16x8 f = *(const bf16x8*)(xw + (size_t)sid * 128 + c0);
#pragma unroll
        for (int k = 0; k < 8; ++k) acc[k] += p * (float)f[k];
    }
#pragma unroll
    for (int off = 16; off <= 32; off <<= 1) {
        ssum += __shfl_xor(ssum, off);
#pragma unroll
        for (int k = 0; k < 8; ++k) acc[k] += __shfl_xor(acc[k], off);
    }
    if (g == 0) {
        const float inv = 1.f / (ssum + 1e-16f);
        bf16x8 o;
#pragma unroll
        for (int k = 0; k < 8; ++k) {
            int c = c0 + k;
            float v = acc[k] * inv + bias[c];
            v = (v - mean[c]) * rsqrtf(var[c] + 1e-5f) * gamma[c] + beta[c];
            v = (v > 0.f) ? v : (__expf(v) - 1.f);
            o[k] = (__bf16)v;
        }
        *(bf16x8*)(out + (size_t)n * 128 + c0) = o;
    }
}

// ---- layer 2: batched gathers + single-pass softmax + bias, fp32 out ------
// R12 shape: eighth-waves (8 lanes x 8ch), 4 edges each.
__global__ __launch_bounds__(256) void agg2_k(
    const int* __restrict__ rowptr, const unsigned short* __restrict__ ssrc,
    const __hip_bfloat16* __restrict__ xw,
    const float* __restrict__ a_s, const float* __restrict__ a_d,
    const float* __restrict__ bias, float* __restrict__ out, int Nn) {
    int n = (blockIdx.x * blockDim.x + threadIdx.x) >> 6;
    int lane = threadIdx.x & 63;
    if (n >= Nn) return;
    const int r0 = rowptr[n];
    const int deg = rowptr[n + 1] - r0;
    const int g = lane >> 3, q = lane & 7;
    const int c0 = q * 8;
    const float adn = a_d[n];

    float ssum = 0.f;
    float acc[8];
#pragma unroll
    for (int k = 0; k < 8; ++k) acc[k] = 0.f;

    int j = 0;
    for (; j + 32 <= deg; j += 32) {
        int sid[4];
#pragma unroll
        for (int b = 0; b < 4; ++b) sid[b] = ssrc[r0 + j + b * 8 + g];
        float as[4];
        bf16x8 f[4];
#pragma unroll
        for (int b = 0; b < 4; ++b) {
            as[b] = a_s[sid[b]];
            f[b] = *(const bf16x8*)(xw + (size_t)sid[b] * 64 + c0);
        }
#pragma unroll
        for (int b = 0; b < 4; ++b) {
            float e = as[b] + adn;
            e = (e > 0.f) ? e : 0.2f * e;
            float p = __expf(e);
            ssum += p;
#pragma unroll
            for (int k = 0; k < 8; ++k) acc[k] += p * (float)f[b][k];
        }
    }
    for (; j < deg; j += 8) {
        int jj = j + g;
        bool ok = jj < deg;
        int sid = ssrc[r0 + (ok ? jj : j)];
        float e = a_s[sid] + adn;
        e = (e > 0.f) ? e : 0.2f * e;
        float p = ok ? __expf(e) : 0.f;
        ssum += p;
        bf16x8 f = *(const bf16x8*)(xw + (size_t)sid * 64 + c0);
#pragma unroll
        for (int k = 0; k < 8; ++k) acc[k] += p * (float)f[k];
    }
#pragma unroll
    for (int off = 8; off <= 32; off <<= 1) {
        ssum += __shfl_xor(ssum, off);
#pragma unroll
        for (int k = 0; k < 8; ++k) acc[k] += __shfl_xor(acc[k], off);
    }
    if (g == 0) {
        const float inv = 1.f / (ssum + 1e-16f);
        float4 o0, o1;
        o0.x = acc[0] * inv + bias[c0];
        o0.y = acc[1] * inv + bias[c0 + 1];
        o0.z = acc[2] * inv + bias[c0 + 2];
        o0.w = acc[3] * inv + bias[c0 + 3];
        o1.x = acc[4] * inv + bias[c0 + 4];
        o1.y = acc[5] * inv + bias[c0 + 5];
        o1.z = acc[6] * inv + bias[c0 + 6];
        o1.w = acc[7] * inv + bias[c0 + 7];
        *(float4*)(out + (size_t)n * 64 + c0) = o0;
        *(float4*)(out + (size_t)n * 64 + c0 + 4) = o1;
    }
}

extern "C" void kernel_launch(void* const* d_in, const int* in_sizes, int n_in,
                              void* d_out, int out_size, void* d_ws, size_t ws_size,
                              hipStream_t stream) {
    const float* x     = (const float*)d_in[0];
    const int*   ei    = (const int*)d_in[1];
    const float* W1    = (const float*)d_in[2];
    const float* as1   = (const float*)d_in[3];
    const float* ad1   = (const float*)d_in[4];
    const float* b1    = (const float*)d_in[5];
    const float* gamma = (const float*)d_in[6];
    const float* beta  = (const float*)d_in[7];
    const float* mean  = (const float*)d_in[8];
    const float* var   = (const float*)d_in[9];
    const float* W2    = (const float*)d_in[10];
    const float* as2   = (const float*)d_in[11];
    const float* ad2   = (const float*)d_in[12];
    const float* b2    = (const float*)d_in[13];
    float* out = (float*)d_out;

    const int N = NNODES;
    const int E = in_sizes[1] / 2;
    const int Etot = E + N;
    const int* esrc = ei;
    const int* edst = ei + E;

    const int NB = (Etot + CHUNK - 1) / CHUNK;          // ~403

    // workspace layout (16-B aligned segments), ~46 MB total
    char* w = (char*)d_ws;
    __hip_bfloat16* xw1 = (__hip_bfloat16*)w; w += (size_t)N * 128 * 2;   // 12.8 MB
    __hip_bfloat16* hbuf = (__hip_bfloat16*)w; w += (size_t)N * 128 * 2;  // 12.8 MB
    __hip_bfloat16* xw2 = (__hip_bfloat16*)w; w += (size_t)N * 64 * 2;    // 6.4 MB
    float* a_s1 = (float*)w; w += (size_t)N * 4 * 4;   // also a_s2 (reuse)
    float* a_d1 = (float*)w; w += (size_t)N * 4 * 4;   // also a_d2 (reuse)
    unsigned int* gbucket = (unsigned int*)w; w += (size_t)Etot * 4 + 16; // 6.6 MB
    int* btot   = (int*)w;  w += (size_t)(BKTS + 4) * 4;
    int* base   = (int*)w;  w += (size_t)(BKTS + 4) * 4;
    int* cursor = (int*)w;  w += (size_t)(BKTS + 4) * 4;
    int* rowptr = (int*)w;  w += (size_t)(N + 8) * 4;
    unsigned short* ssrc_s = (unsigned short*)w; w += (size_t)Etot * 2 + 16; // 3.3 MB
    __hip_bfloat16* wp1 = (__hip_bfloat16*)w; w += 8 * 4 * 64 * 8 * 2;  // 32 KB
    __hip_bfloat16* wp2 = (__hip_bfloat16*)w; w += 4 * 4 * 64 * 8 * 2;  // 16 KB
    float* a_s2 = a_s1; float* a_d2 = a_d1;

    const int TB = 256;
    const int aggBlocks  = (N + 3) / 4;            // one wave/node, 4 waves/block
    const int gemmBlocks = (N / 16 + 3) / 4;       // 3125 row-tiles / 4 waves
    const int wpackBlocks = (8 * 4 * 64 + 4 * 4 * 64 + TB - 1) / TB;   // 3

    // ---- CSR build ----
    hipMemsetAsync(btot, 0, (size_t)BKTS * 4, stream);
    hist_wpack_k<<<NB + wpackBlocks, TB, 0, stream>>>(edst, E, Etot, NB, btot,
                                                      W1, W2, wp1, wp2);
    scan_small_k<<<1, TB, 0, stream>>>(btot, base, cursor, BKTS);
    scatter_bucket_k<<<NB, TB, 0, stream>>>(esrc, edst, E, Etot, cursor, gbucket);
    finalize_k<<<BKTS, TB, 0, stream>>>(gbucket, base, ssrc_s, rowptr, N);

    // ---- layer 1 ----
    gemm_mfma_k<128, false><<<gemmBlocks, TB, 0, stream>>>(x, wp1, xw1,
                                                           as1, ad1, a_s1, a_d1, N);
    agg1_k<<<aggBlocks, TB, 0, stream>>>(rowptr, ssrc_s, xw1, a_s1, a_d1,
                                         b1, gamma, beta, mean, var, hbuf, N);

    // ---- layer 2 ----
    gemm_mfma_k<64, true><<<gemmBlocks, TB, 0, stream>>>(hbuf, wp2, xw2,
                                                         as2, ad2, a_s2, a_d2, N);
    agg2_k<<<aggBlocks, TB, 0, stream>>>(rowptr, ssrc_s, xw2, a_s2, a_d2, b2, out, N);
}

// Round 15
// 252.813 us; speedup vs baseline: 1.0811x; 1.0811x over previous
//
#include <hip/hip_runtime.h>
#include <hip/hip_bf16.h>
#include <hip/hip_fp16.h>

// ---------------------------------------------------------------------------
// GAT 2-layer pipeline. R15: R12 sort chain restored (fastest measured);
// wpack fused into hist dispatch; layer-1 GEMM fused into scatter dispatch
// (independent work overlapped). agg kernels at measured-optimal R12 shapes.
// Fused attention scores in GEMM epilogue; single-pass softmax w/o max-sub;
// MFMA bf16 GEMMs.
// ---------------------------------------------------------------------------

#define NNODES 50000
#define NODE_SHIFT 7                       // 128 nodes per bucket
#define BKTS ((NNODES + 127) / 128)        // 391
#define CHUNK 4096                         // edges per histogram/scatter block
#define CAP 8192                           // max edges per bucket (mean ~4224)

typedef __bf16 bf16x8 __attribute__((ext_vector_type(8)));
typedef float f32x4 __attribute__((ext_vector_type(4)));

// ---------- GEMM body: Y = X @ W (one 16-row tile per wave) -----------------
template <int COLS, bool IN_BF16>
__device__ __forceinline__ void gemm_body(
    int tile, int lane, const void* __restrict__ Xv,
    const __hip_bfloat16* __restrict__ Wp, __hip_bfloat16* __restrict__ Y,
    const float* __restrict__ atts, const float* __restrict__ attd,
    float* __restrict__ a_s, float* __restrict__ a_d, int M) {
    constexpr int NH = (COLS == 128) ? 4 : 1;
    if (tile * 16 >= M) return;
    const int quad = lane >> 4, col = lane & 15;
    const int row = tile * 16 + col;

    bf16x8 afr[4];
    if (IN_BF16) {
        const __hip_bfloat16* X = (const __hip_bfloat16*)Xv;
#pragma unroll
        for (int s = 0; s < 4; ++s)
            afr[s] = *(const bf16x8*)(X + (size_t)row * 128 + s * 32 + quad * 8);
    } else {
        const float* X = (const float*)Xv;
#pragma unroll
        for (int s = 0; s < 4; ++s) {
            const float4* p = (const float4*)(X + (size_t)row * 128 + s * 32 + quad * 8);
            float4 f0 = p[0], f1 = p[1];
            afr[s][0] = (__bf16)f0.x; afr[s][1] = (__bf16)f0.y;
            afr[s][2] = (__bf16)f0.z; afr[s][3] = (__bf16)f0.w;
            afr[s][4] = (__bf16)f1.x; afr[s][5] = (__bf16)f1.y;
            afr[s][6] = (__bf16)f1.z; afr[s][7] = (__bf16)f1.w;
        }
    }

    float asp[4][NH], adp[4][NH];
#pragma unroll
    for (int r = 0; r < 4; ++r)
#pragma unroll
        for (int h = 0; h < NH; ++h) { asp[r][h] = 0.f; adp[r][h] = 0.f; }

    const bf16x8* Wp8 = (const bf16x8*)Wp;
#pragma unroll
    for (int t = 0; t < COLS / 16; ++t) {
        f32x4 acc = {0.f, 0.f, 0.f, 0.f};
#pragma unroll
        for (int s = 0; s < 4; ++s) {
            bf16x8 bfr = Wp8[(t * 4 + s) * 64 + lane];
            acc = __builtin_amdgcn_mfma_f32_16x16x32_bf16(afr[s], bfr, acc, 0, 0, 0);
        }
        const int gc = t * 16 + col;
        const int h = (NH == 4) ? (t >> 1) : 0;
        const float ws = atts[gc], wd = attd[gc];
#pragma unroll
        for (int r = 0; r < 4; ++r) {
            asp[r][h] += acc[r] * ws;
            adp[r][h] += acc[r] * wd;
            Y[(size_t)(tile * 16 + quad * 4 + r) * COLS + gc] = __float2bfloat16(acc[r]);
        }
    }

#pragma unroll
    for (int off = 1; off <= 8; off <<= 1) {
#pragma unroll
        for (int r = 0; r < 4; ++r)
#pragma unroll
            for (int h = 0; h < NH; ++h) {
                asp[r][h] += __shfl_xor(asp[r][h], off);
                adp[r][h] += __shfl_xor(adp[r][h], off);
            }
    }
    if (col == 0) {
#pragma unroll
        for (int r = 0; r < 4; ++r) {
            int rw = tile * 16 + quad * 4 + r;
#pragma unroll
            for (int h = 0; h < NH; ++h) {
                a_s[rw * NH + h] = asp[r][h];
                a_d[rw * NH + h] = adp[r][h];
            }
        }
    }
}

// ---- hist (bucket-major per-chunk histogram) + W-repack fused --------------
__global__ __launch_bounds__(256) void hist_wpack_k(
    const int* __restrict__ edst, int E, int Etot, int NB,
    int* __restrict__ g_hist,
    const float* __restrict__ W1, const float* __restrict__ W2,
    __hip_bfloat16* __restrict__ Wp1, __hip_bfloat16* __restrict__ Wp2) {
    if ((int)blockIdx.x >= NB) {
        constexpr int TOT1 = 8 * 4 * 64;   // COLS=128
        constexpr int TOT2 = 4 * 4 * 64;   // COLS=64
        int i = (blockIdx.x - NB) * 256 + threadIdx.x;
        if (i < TOT1) {
            int l = i & 63, s = (i >> 6) & 3, t = i >> 8;
            int quad = l >> 4, col = l & 15;
#pragma unroll
            for (int j = 0; j < 8; ++j) {
                float f = W1[(s * 32 + quad * 8 + j) * 128 + t * 16 + col];
                Wp1[(size_t)i * 8 + j] = __float2bfloat16(f);
            }
        } else if (i < TOT1 + TOT2) {
            int i2 = i - TOT1;
            int l = i2 & 63, s = (i2 >> 6) & 3, t = i2 >> 8;
            int quad = l >> 4, col = l & 15;
#pragma unroll
            for (int j = 0; j < 8; ++j) {
                float f = W2[(s * 32 + quad * 8 + j) * 64 + t * 16 + col];
                Wp2[(size_t)i2 * 8 + j] = __float2bfloat16(f);
            }
        }
        return;
    }
    __shared__ int h[BKTS];
    for (int b = threadIdx.x; b < BKTS; b += 256) h[b] = 0;
    __syncthreads();
    const int e0 = blockIdx.x * CHUNK;
    const int e1 = min(e0 + CHUNK, Etot);
    for (int i = e0 + threadIdx.x; i < e1; i += 256) {
        int d = (i < E) ? edst[i] : (i - E);
        atomicAdd(&h[d >> NODE_SHIFT], 1);
    }
    __syncthreads();
    for (int b = threadIdx.x; b < BKTS; b += 256)
        g_hist[b * NB + blockIdx.x] = h[b];
}

// ------------------- scans (R12) -------------------------------------------
__global__ __launch_bounds__(256) void scan1_k(const int* __restrict__ cnt,
                                               int* __restrict__ partial,
                                               int* __restrict__ bsum, int Nn) {
    __shared__ int sA[256];
    int i = blockIdx.x * 256 + threadIdx.x;
    sA[threadIdx.x] = (i < Nn) ? cnt[i] : 0;
    __syncthreads();
    for (int off = 1; off < 256; off <<= 1) {
        int u = (threadIdx.x >= off) ? sA[threadIdx.x - off] : 0;
        __syncthreads();
        sA[threadIdx.x] += u;
        __syncthreads();
    }
    if (i < Nn) partial[i] = sA[threadIdx.x];
    if (threadIdx.x == 255) bsum[blockIdx.x] = sA[255];
}

// single-block sequential-tile inclusive scan over nb (nb may exceed 256)
__global__ __launch_bounds__(256) void scan2_k(int* __restrict__ bsum, int nb) {
    __shared__ int sA[256];
    const int t = threadIdx.x;
    int carry = 0;
    for (int base = 0; base < nb; base += 256) {
        int i = base + t;
        sA[t] = (i < nb) ? bsum[i] : 0;
        __syncthreads();
        for (int off = 1; off < 256; off <<= 1) {
            int u = (t >= off) ? sA[t - off] : 0;
            __syncthreads();
            sA[t] += u;
            __syncthreads();
        }
        if (i < nb) bsum[i] = sA[t] + carry;
        carry += sA[255];
        __syncthreads();
    }
}

__global__ void scan3_k(const int* __restrict__ partial, const int* __restrict__ bsum,
                        int* __restrict__ out, int Nn) {
    int i = blockIdx.x * 256 + threadIdx.x;
    if (i >= Nn) return;
    int b = blockIdx.x;
    int off = (b == 0) ? 0 : bsum[b - 1];
    out[i + 1] = partial[i] + off;
    if (i == 0) out[0] = 0;
}

// ---- scatter (R12, scanned LDS cursors) + layer-1 GEMM fused ---------------
__global__ __launch_bounds__(256) void scatter_gemm_k(
    const int* __restrict__ esrc, const int* __restrict__ edst,
    int E, int Etot, int NB, const int* __restrict__ scanned,
    unsigned int* __restrict__ gbucket,
    const float* __restrict__ X, const __hip_bfloat16* __restrict__ Wp1,
    __hip_bfloat16* __restrict__ Y1,
    const float* __restrict__ atts, const float* __restrict__ attd,
    float* __restrict__ a_s, float* __restrict__ a_d, int M) {
    if ((int)blockIdx.x >= NB) {
        const int wid = threadIdx.x >> 6, lane = threadIdx.x & 63;
        const int tile = (blockIdx.x - NB) * 4 + wid;
        gemm_body<128, false>(tile, lane, X, Wp1, Y1, atts, attd, a_s, a_d, M);
        return;
    }
    __shared__ int cur[BKTS];
    for (int b = threadIdx.x; b < BKTS; b += 256)
        cur[b] = scanned[b * NB + blockIdx.x];
    __syncthreads();
    const int e0 = blockIdx.x * CHUNK;
    const int e1 = min(e0 + CHUNK, Etot);
    for (int i = e0 + threadIdx.x; i < e1; i += 256) {
        int s, d;
        if (i < E) { s = esrc[i]; d = edst[i]; }
        else       { s = i - E;   d = i - E; }
        int pos = atomicAdd(&cur[d >> NODE_SHIFT], 1);
        gbucket[pos] = ((unsigned)(d & 127) << 16) | (unsigned)s;
    }
}

// ---- finalize: per-bucket LDS counting sort -> ssrc (ushort) + rowptr ------
__global__ __launch_bounds__(256) void finalize_k(
    const unsigned int* __restrict__ gbucket, const int* __restrict__ scanned,
    int NB, int Etot, unsigned short* __restrict__ ssrc,
    int* __restrict__ rowptr, int Nn) {
    const int b = blockIdx.x;
    const int base = scanned[b * NB];
    const int end = (b + 1 < BKTS) ? scanned[(b + 1) * NB] : Etot;
    const int cnt = end - base;
    const int t = threadIdx.x;

    __shared__ unsigned int keys[CAP];
    __shared__ int hist[128], sA[128], cur[128];

    for (int i = t; i < cnt; i += 256) keys[i] = gbucket[base + i];
    if (t < 128) hist[t] = 0;
    __syncthreads();
    for (int i = t; i < cnt; i += 256) atomicAdd(&hist[keys[i] >> 16], 1);
    __syncthreads();
    if (t < 128) sA[t] = hist[t];
    __syncthreads();
    for (int off = 1; off < 128; off <<= 1) {
        int u = 0;
        if (t < 128 && t >= off) u = sA[t - off];
        __syncthreads();
        if (t < 128) sA[t] += u;
        __syncthreads();
    }
    if (t < 128) {
        int excl = sA[t] - hist[t];
        cur[t] = excl;
        int node = b * 128 + t;
        if (node <= Nn) rowptr[node] = base + excl;  // node==Nn -> rowptr[N]=Etot
    }
    __syncthreads();
    for (int i = t; i < cnt; i += 256) {
        unsigned k = keys[i];
        int p = atomicAdd(&cur[k >> 16], 1);
        ssrc[base + p] = (unsigned short)(k & 0xFFFFu);
    }
}

// ---------- standalone layer-2 GEMM ----------------------------------------
template <int COLS, bool IN_BF16>
__global__ __launch_bounds__(256) void gemm_mfma_k(
    const void* __restrict__ Xv, const __hip_bfloat16* __restrict__ Wp,
    __hip_bfloat16* __restrict__ Y,
    const float* __restrict__ atts, const float* __restrict__ attd,
    float* __restrict__ a_s, float* __restrict__ a_d, int M) {
    const int wid = threadIdx.x >> 6, lane = threadIdx.x & 63;
    const int tile = blockIdx.x * 4 + wid;
    gemm_body<COLS, IN_BF16>(tile, lane, Xv, Wp, Y, atts, attd, a_s, a_d, M);
}

// ---- layer 1: batched gathers + single-pass softmax + bias/BN/ELU ---------
// R12 shape: quarter-waves (16 lanes x 8ch), 4 edges/qwave, VGPR-lean.
__global__ __launch_bounds__(256) void agg1_k(
    const int* __restrict__ rowptr, const unsigned short* __restrict__ ssrc,
    const __hip_bfloat16* __restrict__ xw,
    const float* __restrict__ a_s, const float* __restrict__ a_d,
    const float* __restrict__ bias,
    const float* __restrict__ gamma, const float* __restrict__ beta,
    const float* __restrict__ mean, const float* __restrict__ var,
    __hip_bfloat16* __restrict__ out, int Nn) {
    int n = (blockIdx.x * blockDim.x + threadIdx.x) >> 6;
    int lane = threadIdx.x & 63;
    if (n >= Nn) return;
    const int r0 = rowptr[n];
    const int deg = rowptr[n + 1] - r0;
    const int g = lane >> 4, q = lane & 15;
    const int c0 = q * 8;          // channels c0..c0+7
    const int h = q >> 2;          // head = c0/32
    const float adh = a_d[n * 4 + h];

    float ssum = 0.f;
    float acc[8];
#pragma unroll
    for (int k = 0; k < 8; ++k) acc[k] = 0.f;

    int j = 0;
    for (; j + 16 <= deg; j += 16) {
        int sid[4];
#pragma unroll
        for (int b = 0; b < 4; ++b) sid[b] = ssrc[r0 + j + b * 4 + g];
        float as[4];
        bf16x8 f[4];
#pragma unroll
        for (int b = 0; b < 4; ++b) {
            as[b] = a_s[sid[b] * 4 + h];
            f[b] = *(const bf16x8*)(xw + (size_t)sid[b] * 128 + c0);
        }
#pragma unroll
        for (int b = 0; b < 4; ++b) {
            float e = as[b] + adh;
            e = (e > 0.f) ? e : 0.2f * e;
            float p = __expf(e);
            ssum += p;
#pragma unroll
            for (int k = 0; k < 8; ++k) acc[k] += p * (float)f[b][k];
        }
    }
    for (; j < deg; j += 4) {
        int jj = j + g;
        bool ok = jj < deg;
        int sid = ssrc[r0 + (ok ? jj : j)];
        float e = a_s[sid * 4 + h] + adh;
        e = (e > 0.f) ? e : 0.2f * e;
        float p = ok ? __expf(e) : 0.f;
        ssum += p;
        bf16x8 f = *(const bf16x8*)(xw + (size_t)sid * 128 + c0);
#pragma unroll
        for (int k = 0; k < 8; ++k) acc[k] += p * (float)f[k];
    }
#pragma unroll
    for (int off = 16; off <= 32; off <<= 1) {
        ssum += __shfl_xor(ssum, off);
#pragma unroll
        for (int k = 0; k < 8; ++k) acc[k] += __shfl_xor(acc[k], off);
    }
    if (g == 0) {
        const float inv = 1.f / (ssum + 1e-16f);
        bf16x8 o;
#pragma unroll
        for (int k = 0; k < 8; ++k) {
            int c = c0 + k;
            float v = acc[k] * inv + bias[c];
            v = (v - mean[c]) * rsqrtf(var[c] + 1e-5f) * gamma[c] + beta[c];
            v = (v > 0.f) ? v : (__expf(v) - 1.f);
            o[k] = (__bf16)v;
        }
        *(bf16x8*)(out + (size_t)n * 128 + c0) = o;
    }
}

// ---- layer 2: batched gathers + single-pass softmax + bias, fp32 out ------
// R12 shape: eighth-waves (8 lanes x 8ch), 4 edges each.
__global__ __launch_bounds__(256) void agg2_k(
    const int* __restrict__ rowptr, const unsigned short* __restrict__ ssrc,
    const __hip_bfloat16* __restrict__ xw,
    const float* __restrict__ a_s, const float* __restrict__ a_d,
    const float* __restrict__ bias, float* __restrict__ out, int Nn) {
    int n = (blockIdx.x * blockDim.x + threadIdx.x) >> 6;
    int lane = threadIdx.x & 63;
    if (n >= Nn) return;
    const int r0 = rowptr[n];
    const int deg = rowptr[n + 1] - r0;
    const int g = lane >> 3, q = lane & 7;
    const int c0 = q * 8;
    const float adn = a_d[n];

    float ssum = 0.f;
    float acc[8];
#pragma unroll
    for (int k = 0; k < 8; ++k) acc[k] = 0.f;

    int j = 0;
    for (; j + 32 <= deg; j += 32) {
        int sid[4];
#pragma unroll
        for (int b = 0; b < 4; ++b) sid[b] = ssrc[r0 + j + b * 8 + g];
        float as[4];
        bf16x8 f[4];
#pragma unroll
        for (int b = 0; b < 4; ++b) {
            as[b] = a_s[sid[b]];
            f[b] = *(const bf16x8*)(xw + (size_t)sid[b] * 64 + c0);
        }
#pragma unroll
        for (int b = 0; b < 4; ++b) {
            float e = as[b] + adn;
            e = (e > 0.f) ? e : 0.2f * e;
            float p = __expf(e);
            ssum += p;
#pragma unroll
            for (int k = 0; k < 8; ++k) acc[k] += p * (float)f[b][k];
        }
    }
    for (; j < deg; j += 8) {
        int jj = j + g;
        bool ok = jj < deg;
        int sid = ssrc[r0 + (ok ? jj : j)];
        float e = a_s[sid] + adn;
        e = (e > 0.f) ? e : 0.2f * e;
        float p = ok ? __expf(e) : 0.f;
        ssum += p;
        bf16x8 f = *(const bf16x8*)(xw + (size_t)sid * 64 + c0);
#pragma unroll
        for (int k = 0; k < 8; ++k) acc[k] += p * (float)f[k];
    }
#pragma unroll
    for (int off = 8; off <= 32; off <<= 1) {
        ssum += __shfl_xor(ssum, off);
#pragma unroll
        for (int k = 0; k < 8; ++k) acc[k] += __shfl_xor(acc[k], off);
    }
    if (g == 0) {
        const float inv = 1.f / (ssum + 1e-16f);
        float4 o0, o1;
        o0.x = acc[0] * inv + bias[c0];
        o0.y = acc[1] * inv + bias[c0 + 1];
        o0.z = acc[2] * inv + bias[c0 + 2];
        o0.w = acc[3] * inv + bias[c0 + 3];
        o1.x = acc[4] * inv + bias[c0 + 4];
        o1.y = acc[5] * inv + bias[c0 + 5];
        o1.z = acc[6] * inv + bias[c0 + 6];
        o1.w = acc[7] * inv + bias[c0 + 7];
        *(float4*)(out + (size_t)n * 64 + c0) = o0;
        *(float4*)(out + (size_t)n * 64 + c0 + 4) = o1;
    }
}

extern "C" void kernel_launch(void* const* d_in, const int* in_sizes, int n_in,
                              void* d_out, int out_size, void* d_ws, size_t ws_size,
                              hipStream_t stream) {
    const float* x     = (const float*)d_in[0];
    const int*   ei    = (const int*)d_in[1];
    const float* W1    = (const float*)d_in[2];
    const float* as1   = (const float*)d_in[3];
    const float* ad1   = (const float*)d_in[4];
    const float* b1    = (const float*)d_in[5];
    const float* gamma = (const float*)d_in[6];
    const float* beta  = (const float*)d_in[7];
    const float* mean  = (const float*)d_in[8];
    const float* var   = (const float*)d_in[9];
    const float* W2    = (const float*)d_in[10];
    const float* as2   = (const float*)d_in[11];
    const float* ad2   = (const float*)d_in[12];
    const float* b2    = (const float*)d_in[13];
    float* out = (float*)d_out;

    const int N = NNODES;
    const int E = in_sizes[1] / 2;
    const int Etot = E + N;
    const int* esrc = ei;
    const int* edst = ei + E;

    const int NB = (Etot + CHUNK - 1) / CHUNK;          // ~403
    const int flatN = BKTS * NB;                        // ~157k

    // workspace layout (16-B aligned segments), ~48 MB total
    char* w = (char*)d_ws;
    __hip_bfloat16* xw1 = (__hip_bfloat16*)w; w += (size_t)N * 128 * 2;   // 12.8 MB
    __hip_bfloat16* hbuf = (__hip_bfloat16*)w; w += (size_t)N * 128 * 2;  // 12.8 MB
    __hip_bfloat16* xw2 = (__hip_bfloat16*)w; w += (size_t)N * 64 * 2;    // 6.4 MB
    float* a_s1 = (float*)w; w += (size_t)N * 4 * 4;   // also a_s2 (reuse)
    float* a_d1 = (float*)w; w += (size_t)N * 4 * 4;   // also a_d2 (reuse)
    unsigned int* gbucket = (unsigned int*)w; w += (size_t)Etot * 4 + 16; // 6.6 MB
    int* g_hist  = (int*)w;  w += (size_t)flatN * 4 + 16;  // ~630 KB
    int* partial = (int*)w;  w += (size_t)flatN * 4 + 16;
    int* scanned = (int*)w;  w += (size_t)(flatN + 4) * 4 + 16;
    int* bsum    = (int*)w;  w += 4096;
    int* rowptr  = (int*)w;  w += (size_t)(N + 8) * 4;
    unsigned short* ssrc_s = (unsigned short*)w; w += (size_t)Etot * 2 + 16; // 3.3 MB
    __hip_bfloat16* wp1 = (__hip_bfloat16*)w; w += 8 * 4 * 64 * 8 * 2;  // 32 KB
    __hip_bfloat16* wp2 = (__hip_bfloat16*)w; w += 4 * 4 * 64 * 8 * 2;  // 16 KB
    float* a_s2 = a_s1; float* a_d2 = a_d1;

    const int TB = 256;
    const int nb2 = (flatN + 255) / 256;           // scan1/scan3 blocks (~616)
    const int aggBlocks  = (N + 3) / 4;            // one wave/node, 4 waves/block
    const int gemmBlocks = (N / 16 + 3) / 4;       // 3125 row-tiles / 4 waves
    const int wpackBlocks = (8 * 4 * 64 + 4 * 4 * 64 + TB - 1) / TB;   // 3

    // ---- CSR build (hist fused with W repack) ----
    hist_wpack_k<<<NB + wpackBlocks, TB, 0, stream>>>(edst, E, Etot, NB, g_hist,
                                                      W1, W2, wp1, wp2);
    scan1_k<<<nb2, TB, 0, stream>>>(g_hist, partial, bsum, flatN);
    scan2_k<<<1, TB, 0, stream>>>(bsum, nb2);
    scan3_k<<<nb2, TB, 0, stream>>>(partial, bsum, scanned, flatN);
    // scatter + layer-1 GEMM fused (independent work, one dispatch)
    scatter_gemm_k<<<NB + gemmBlocks, TB, 0, stream>>>(
        esrc, edst, E, Etot, NB, scanned, gbucket,
        x, wp1, xw1, as1, ad1, a_s1, a_d1, N);
    finalize_k<<<BKTS, TB, 0, stream>>>(gbucket, scanned, NB, Etot, ssrc_s, rowptr, N);

    // ---- layer 1 aggregation ----
    agg1_k<<<aggBlocks, TB, 0, stream>>>(rowptr, ssrc_s, xw1, a_s1, a_d1,
                                         b1, gamma, beta, mean, var, hbuf, N);

    // ---- layer 2 ----
    gemm_mfma_k<64, true><<<gemmBlocks, TB, 0, stream>>>(hbuf, wp2, xw2,
                                                         as2, ad2, a_s2, a_d2, N);
    agg2_k<<<aggBlocks, TB, 0, stream>>>(rowptr, ssrc_s, xw2, a_s2, a_d2, b2, out, N);
}